// Round 9
// baseline (321.919 us; speedup 1.0000x reference)
//
#include <hip/hip_runtime.h>

#define F1 128
#define F2 8
#define CAP 64       // fixed CSR capacity per node (deg ~ Poisson(16); P(>64) ~ 1e-20)
#define RH 8192      // nodes per range (32 KB LDS bins)
#define ECH 16384    // edges per chunk (multiple of 2048)
#define BK 32        // gemm1 K-chunk

typedef unsigned short us8 __attribute__((ext_vector_type(8)));

__device__ inline unsigned short f2bf(float f) {
  unsigned u = __float_as_uint(f);
  u += 0x7FFF + ((u >> 16) & 1);   // round-to-nearest-even
  return (unsigned short)(u >> 16);
}
__device__ inline float bf2f(unsigned short h) {
  return __uint_as_float(((unsigned)h) << 16);
}

// ---------- pack indices to ushort (N < 65536), pad with 0xFFFF ----------
__global__ void k_pack(const int* __restrict__ src, const int* __restrict__ dst,
                       unsigned short* __restrict__ src16, unsigned short* __restrict__ dst16,
                       int E, int Epad) {
  int e = blockIdx.x * 256 + threadIdx.x;
  if (e < Epad) {
    src16[e] = (e < E) ? (unsigned short)src[e] : (unsigned short)0xFFFF;
    dst16[e] = (e < E) ? (unsigned short)dst[e] : (unsigned short)0xFFFF;
  }
}

// ---------- pass 1: per-(range,chunk) histograms of src AND dst, LDS-only atomics ----------
__global__ __launch_bounds__(256) void k_hist(const unsigned short* __restrict__ src16,
                                              const unsigned short* __restrict__ dst16,
                                              int* __restrict__ partialA,
                                              int* __restrict__ partialB,
                                              int Epad, int N) {
  __shared__ int binsA[RH];
  __shared__ int binsB[RH];
  int range0 = blockIdx.x * RH;
  int c = blockIdx.y;
  int t = threadIdx.x;
  for (int i = t; i < RH; i += 256) { binsA[i] = 0; binsB[i] = 0; }
  __syncthreads();
  int e0 = c * ECH, e1 = min(e0 + ECH, Epad);
  for (int base = e0 + t * 8; base < e1; base += 2048) {
    us8 a = *(const us8*)&src16[base];
    us8 b = *(const us8*)&dst16[base];
#pragma unroll
    for (int j = 0; j < 8; ++j) {
      int sn = (int)a[j] - range0;
      if ((unsigned)sn < (unsigned)RH) atomicAdd(&binsA[sn], 1);
      int dn = (int)b[j] - range0;
      if ((unsigned)dn < (unsigned)RH) atomicAdd(&binsB[dn], 1);
    }
  }
  __syncthreads();
  for (int i = t; i < RH; i += 256) {
    int n = range0 + i;
    if (n < N) {
      partialA[c * N + n] = binsA[i];
      partialB[c * N + n] = binsB[i];
    }
  }
}

// ---------- per-node chunk-prefix starts + cnt + norms ----------
__global__ void k_starts(const int* __restrict__ partialA, const int* __restrict__ partialB,
                         int* __restrict__ starts, int* __restrict__ cnt,
                         float* __restrict__ norm_src, float* __restrict__ norm_dst,
                         int N, int NCH) {
  int n = blockIdx.x * 256 + threadIdx.x;
  if (n < N) {
    int dout = 0;
    for (int c = 0; c < NCH; ++c) dout += partialA[c * N + n];
    int run = n * CAP;
    for (int c = 0; c < NCH; ++c) {
      starts[c * N + n] = run;
      run += partialB[c * N + n];
    }
    int din = run - n * CAP;
    cnt[n] = min(din, CAP);
    norm_src[n] = dout > 0 ? rsqrtf((float)dout) : 0.f;
    norm_dst[n] = din > 0 ? rsqrtf((float)din) : 0.f;
  }
}

// ---------- pass 2: scatter into fixed-cap CSR via LDS cursors ----------
__global__ __launch_bounds__(256) void k_scatter(const unsigned short* __restrict__ src16,
                                                 const unsigned short* __restrict__ dst16,
                                                 const int* __restrict__ starts,
                                                 unsigned short* __restrict__ esrc16,
                                                 int Epad, int N) {
  __shared__ int cur[RH];
  int range0 = blockIdx.x * RH;
  int c = blockIdx.y;
  int t = threadIdx.x;
  for (int i = t; i < RH; i += 256) {
    int n = range0 + i;
    cur[i] = (n < N) ? starts[c * N + n] : 0;
  }
  __syncthreads();
  int e0 = c * ECH, e1 = min(e0 + ECH, Epad);
  for (int base = e0 + t * 8; base < e1; base += 2048) {
    us8 a = *(const us8*)&src16[base];
    us8 b = *(const us8*)&dst16[base];
#pragma unroll
    for (int j = 0; j < 8; ++j) {
      int dn = (int)b[j] - range0;
      if ((unsigned)dn < (unsigned)RH) {
        int node = range0 + dn;
        int p = atomicAdd(&cur[dn], 1);
        if (p < (node + 1) * CAP) esrc16[p] = a[j];
      }
    }
  }
}

// ---------- GEMM1: 128x128 tile, BK=32, 8x8 register tile per thread ----------
__global__ __launch_bounds__(256) void k_gemm1(const float* __restrict__ x,
                                               const float* __restrict__ W1,
                                               const float* __restrict__ norm_src,
                                               unsigned short* __restrict__ h1n, int N) {
  __shared__ float xsT[BK][132];   // [k][row], pad -> conflict-free tr reads
  __shared__ float Wl[BK][132];    // [k][col]
  int row0 = blockIdx.x * 128;
  int tid = threadIdx.x;
  int tc = tid & 15;    // col group of 8
  int tr = tid >> 4;    // row group of 8
  float acc[8][8] = {{0.f}};

  for (int kb = 0; kb < 128; kb += BK) {
    __syncthreads();
#pragma unroll
    for (int it = 0; it < 4; ++it) {
      int i = tid + it * 256;
      int r = i >> 3, kq = i & 7;
      int grow = row0 + r;
      float4 v = make_float4(0.f, 0.f, 0.f, 0.f);
      if (grow < N) v = *(const float4*)&x[(size_t)grow * 128 + kb + kq * 4];
      xsT[kq * 4 + 0][r] = v.x;
      xsT[kq * 4 + 1][r] = v.y;
      xsT[kq * 4 + 2][r] = v.z;
      xsT[kq * 4 + 3][r] = v.w;
    }
#pragma unroll
    for (int it = 0; it < 4; ++it) {
      int i = tid + it * 256;
      int k = i >> 5, c4 = i & 31;
      *(float4*)&Wl[k][c4 * 4] = *(const float4*)&W1[(size_t)(kb + k) * 128 + c4 * 4];
    }
    __syncthreads();
#pragma unroll 2
    for (int k = 0; k < BK; ++k) {
      float4 xa = *(float4*)&xsT[k][tr * 8];
      float4 xb = *(float4*)&xsT[k][tr * 8 + 4];
      float4 wa = *(float4*)&Wl[k][tc * 8];
      float4 wb = *(float4*)&Wl[k][tc * 8 + 4];
      float xs[8] = {xa.x, xa.y, xa.z, xa.w, xb.x, xb.y, xb.z, xb.w};
      float ws[8] = {wa.x, wa.y, wa.z, wa.w, wb.x, wb.y, wb.z, wb.w};
#pragma unroll
      for (int i = 0; i < 8; ++i)
#pragma unroll
        for (int j = 0; j < 8; ++j) acc[i][j] += xs[i] * ws[j];
    }
  }
#pragma unroll
  for (int i = 0; i < 8; ++i) {
    int grow = row0 + tr * 8 + i;
    if (grow < N) {
      float ns = norm_src[grow];
      us8 o;
#pragma unroll
      for (int j = 0; j < 8; ++j) o[j] = f2bf(acc[i][j] * ns);
      *(us8*)&h1n[(size_t)grow * 128 + tc * 8] = o;
    }
  }
}

// ---------- fused layer-1 aggregation + ReLU + GEMM2 (W2 in LDS, not registers) ----------
// One wave per dst node. Gather loop identical to the unfused version; only the
// epilogue touches W2, via ds_read -> no W2 values live across the gather loop.
__global__ __launch_bounds__(256) void k_agg1f(const unsigned short* __restrict__ h1n,
                                               const int* __restrict__ cnt,
                                               const unsigned short* __restrict__ esrc16,
                                               const float* __restrict__ norm_dst,
                                               const float* __restrict__ norm_src,
                                               const float* __restrict__ b1,
                                               const float* __restrict__ W2,
                                               float* __restrict__ h2n, int N) {
  __shared__ float W2l[128 * 8];   // 4 KB
  int tid = threadIdx.x;
  for (int i = tid; i < 1024; i += 256) W2l[i] = W2[i];
  __syncthreads();

  int wid = (blockIdx.x * 256 + tid) >> 6;
  int lane = tid & 63;
  if (wid >= N) return;
  int q = lane >> 4;
  int fl = lane & 15;
  int i0 = wid * CAP;
  int i1 = i0 + cnt[wid];
  float acc[8] = {0.f, 0.f, 0.f, 0.f, 0.f, 0.f, 0.f, 0.f};
  for (int i = i0; i < i1; i += 64) {
    int cnt64 = min(64, i1 - i);
    int eid = (i + lane < i1) ? (int)esrc16[i + lane] : -1;
    for (int t = 0; t < cnt64; t += 4) {
      int s = __shfl(eid, t + q);
      if (s >= 0) {
        us8 v = *(const us8*)&h1n[(size_t)s * 128 + fl * 8];
#pragma unroll
        for (int j = 0; j < 8; ++j) acc[j] += bf2f(v[j]);
      }
    }
  }
#pragma unroll
  for (int j = 0; j < 8; ++j) acc[j] += __shfl_down(acc[j], 32);
#pragma unroll
  for (int j = 0; j < 8; ++j) acc[j] += __shfl_down(acc[j], 16);
  // lanes<16 hold the full h1 row (feats fl*8..fl*8+7)
  float nd = norm_dst[wid];
  float4 bb0 = *(const float4*)&b1[fl * 8];
  float4 bb1 = *(const float4*)&b1[fl * 8 + 4];
  float r[8];
  r[0] = fmaxf(acc[0] * nd + bb0.x, 0.f);
  r[1] = fmaxf(acc[1] * nd + bb0.y, 0.f);
  r[2] = fmaxf(acc[2] * nd + bb0.z, 0.f);
  r[3] = fmaxf(acc[3] * nd + bb0.w, 0.f);
  r[4] = fmaxf(acc[4] * nd + bb1.x, 0.f);
  r[5] = fmaxf(acc[5] * nd + bb1.y, 0.f);
  r[6] = fmaxf(acc[6] * nd + bb1.z, 0.f);
  r[7] = fmaxf(acc[7] * nd + bb1.w, 0.f);
  float4 pa = make_float4(0.f, 0.f, 0.f, 0.f);
  float4 pb = make_float4(0.f, 0.f, 0.f, 0.f);
#pragma unroll
  for (int jj = 0; jj < 8; ++jj) {
    float4 wa = *(const float4*)&W2l[(fl * 8 + jj) * 8];
    float4 wb = *(const float4*)&W2l[(fl * 8 + jj) * 8 + 4];
    pa.x += r[jj] * wa.x; pa.y += r[jj] * wa.y;
    pa.z += r[jj] * wa.z; pa.w += r[jj] * wa.w;
    pb.x += r[jj] * wb.x; pb.y += r[jj] * wb.y;
    pb.z += r[jj] * wb.z; pb.w += r[jj] * wb.w;
  }
  // tree-reduce over lanes 0..15
#pragma unroll
  for (int d = 8; d >= 1; d >>= 1) {
    pa.x += __shfl_down(pa.x, d); pa.y += __shfl_down(pa.y, d);
    pa.z += __shfl_down(pa.z, d); pa.w += __shfl_down(pa.w, d);
    pb.x += __shfl_down(pb.x, d); pb.y += __shfl_down(pb.y, d);
    pb.z += __shfl_down(pb.z, d); pb.w += __shfl_down(pb.w, d);
  }
  if (lane == 0) {
    float ns = norm_src[wid];
    pa.x *= ns; pa.y *= ns; pa.z *= ns; pa.w *= ns;
    pb.x *= ns; pb.y *= ns; pb.z *= ns; pb.w *= ns;
    *(float4*)&h2n[(size_t)wid * 8] = pa;
    *(float4*)&h2n[(size_t)wid * 8 + 4] = pb;
  }
}

// ---------- layer-2 aggregation + mean-pool: LDS pre-reduction ----------
__global__ __launch_bounds__(256) void k_agg2pool(const float* __restrict__ h2n,
                                                  const int* __restrict__ cnt,
                                                  const unsigned short* __restrict__ esrc16,
                                                  const float* __restrict__ norm_dst,
                                                  const float* __restrict__ b2,
                                                  const int* __restrict__ gids,
                                                  float* __restrict__ gsum, int N) {
  __shared__ float bins[16 * 8];
  __shared__ int sg0;
  int tid = threadIdx.x;
  if (tid < 128) bins[tid] = 0.f;
  int base = blockIdx.x * 32;
  if (tid == 0) sg0 = gids[min(base, N - 1)];
  __syncthreads();
  int node = base + (tid >> 3);
  int j = tid & 7;
  if (node < N) {
    int i0 = node * CAP;
    int i1 = i0 + cnt[node];
    float acc = 0.f;
    for (int i = i0; i < i1; i += 8) {
      int c8 = min(8, i1 - i);
      int eid = (i + j < i1) ? (int)esrc16[i + j] : 0;
      for (int t = 0; t < c8; ++t) {
        int s = __shfl(eid, t, 8);
        acc += h2n[s * 8 + j];
      }
    }
    float r = acc * norm_dst[node] + b2[j];
    int delta = gids[node] - sg0;
    if (delta < 16) atomicAdd(&bins[delta * 8 + j], r);
    else atomicAdd(&gsum[gids[node] * 8 + j], r);
  }
  __syncthreads();
  if (tid < 128) {
    float v = bins[tid];
    if (v != 0.f) atomicAdd(&gsum[(sg0 + (tid >> 3)) * 8 + (tid & 7)], v);
  }
}

// ---------- final ----------
__global__ void k_final(const float* __restrict__ gsum, const int* __restrict__ gids,
                        float* __restrict__ out, int NG, int N) {
  int i = blockIdx.x * 256 + threadIdx.x;
  if (i < NG * F2) {
    int g = i >> 3;
    int lo = 0, hi = N;
    while (lo < hi) { int m = (lo + hi) >> 1; if (gids[m] < g) lo = m + 1; else hi = m; }
    int lb = lo;
    lo = 0; hi = N;
    while (lo < hi) { int m = (lo + hi) >> 1; if (gids[m] <= g) lo = m + 1; else hi = m; }
    int cnt = lo - lb;
    out[i] = gsum[i] / fmaxf((float)cnt, 1.f);
  }
}

extern "C" void kernel_launch(void* const* d_in, const int* in_sizes, int n_in,
                              void* d_out, int out_size, void* d_ws, size_t ws_size,
                              hipStream_t stream) {
  const float* x  = (const float*)d_in[0];
  const float* W1 = (const float*)d_in[1];
  const float* b1 = (const float*)d_in[2];
  const float* W2 = (const float*)d_in[3];
  const float* b2 = (const float*)d_in[4];
  const int* src  = (const int*)d_in[5];
  const int* dst  = (const int*)d_in[6];
  const int* gids = (const int*)d_in[7];
  int N = in_sizes[0] / F1;
  int E = in_sizes[5];
  int NG = out_size / F2;
  float* out = (float*)d_out;

  int Epad = (E + 2047) & ~2047;            // multiple of 256*8
  int NR  = (N + RH - 1) / RH;              // node ranges
  int NCH = (Epad + ECH - 1) / ECH;         // edge chunks

  char* p = (char*)d_ws;
  auto alloc = [&](size_t bytes) -> void* {
    void* r = (void*)p;
    p += (bytes + 255) & ~(size_t)255;
    return r;
  };
  float* gsum    = (float*)alloc((size_t)NG * F2 * 4);       // zeroed
  size_t zero_bytes = (size_t)((char*)p - (char*)gsum);
  unsigned short* src16 = (unsigned short*)alloc((size_t)Epad * 2);
  unsigned short* dst16 = (unsigned short*)alloc((size_t)Epad * 2);
  int* cnt       = (int*)alloc((size_t)N * 4);
  float* norm_src = (float*)alloc((size_t)N * 4);
  float* norm_dst = (float*)alloc((size_t)N * 4);
  unsigned short* esrc16 = (unsigned short*)alloc((size_t)N * CAP * 2);
  unsigned short* h1n = (unsigned short*)alloc((size_t)N * F1 * 2);
  float* h2n     = (float*)alloc((size_t)N * F2 * 4);
  int* partialA  = (int*)alloc((size_t)NCH * N * 4);
  int* partialB  = (int*)alloc((size_t)NCH * N * 4);
  int* starts    = (int*)alloc((size_t)NCH * N * 4);
  (void)ws_size; (void)n_in;

  hipMemsetAsync(gsum, 0, zero_bytes, stream);

  k_pack<<<(Epad + 255) / 256, 256, 0, stream>>>(src, dst, src16, dst16, E, Epad);
  k_hist<<<dim3(NR, NCH), 256, 0, stream>>>(src16, dst16, partialA, partialB, Epad, N);
  k_starts<<<(N + 255) / 256, 256, 0, stream>>>(partialA, partialB, starts, cnt,
                                                norm_src, norm_dst, N, NCH);
  k_scatter<<<dim3(NR, NCH), 256, 0, stream>>>(src16, dst16, starts, esrc16, Epad, N);
  k_gemm1<<<(N + 127) / 128, 256, 0, stream>>>(x, W1, norm_src, h1n, N);
  k_agg1f<<<(N + 3) / 4, 256, 0, stream>>>(h1n, cnt, esrc16, norm_dst, norm_src, b1, W2, h2n, N);
  k_agg2pool<<<((N * 8 + 255) / 256), 256, 0, stream>>>(h2n, cnt, esrc16, norm_dst, b2, gids, gsum, N);
  k_final<<<(NG * F2 + 255) / 256, 256, 0, stream>>>(gsum, gids, out, NG, N);
}

// Round 10
// 259.051 us; speedup vs baseline: 1.2427x; 1.2427x over previous
//
#include <hip/hip_runtime.h>

#define F1 128
#define F2 8
#define CAP 64       // fixed CSR capacity per node (deg ~ Poisson(16); P(>64) ~ 1e-20)
#define RH 8192      // nodes per range (32 KB LDS bins)
#define ECH 16384    // edges per chunk (multiple of 2048)
#define BK 32        // gemm1 K-chunk

typedef unsigned short us8 __attribute__((ext_vector_type(8)));

__device__ inline unsigned short f2bf(float f) {
  unsigned u = __float_as_uint(f);
  u += 0x7FFF + ((u >> 16) & 1);   // round-to-nearest-even
  return (unsigned short)(u >> 16);
}
__device__ inline float bf2f(unsigned short h) {
  return __uint_as_float(((unsigned)h) << 16);
}

// ---------- pack indices to ushort (N < 65536), pad with 0xFFFF ----------
__global__ void k_pack(const int* __restrict__ src, const int* __restrict__ dst,
                       unsigned short* __restrict__ src16, unsigned short* __restrict__ dst16,
                       int E, int Epad) {
  int e = blockIdx.x * 256 + threadIdx.x;
  if (e < Epad) {
    src16[e] = (e < E) ? (unsigned short)src[e] : (unsigned short)0xFFFF;
    dst16[e] = (e < E) ? (unsigned short)dst[e] : (unsigned short)0xFFFF;
  }
}

// ---------- pass 1: per-(range,chunk) histograms of src AND dst, LDS-only atomics ----------
__global__ __launch_bounds__(256) void k_hist(const unsigned short* __restrict__ src16,
                                              const unsigned short* __restrict__ dst16,
                                              int* __restrict__ partialA,
                                              int* __restrict__ partialB,
                                              int Epad, int N) {
  __shared__ int binsA[RH];
  __shared__ int binsB[RH];
  int range0 = blockIdx.x * RH;
  int c = blockIdx.y;
  int t = threadIdx.x;
  for (int i = t; i < RH; i += 256) { binsA[i] = 0; binsB[i] = 0; }
  __syncthreads();
  int e0 = c * ECH, e1 = min(e0 + ECH, Epad);
  for (int base = e0 + t * 8; base < e1; base += 2048) {
    us8 a = *(const us8*)&src16[base];
    us8 b = *(const us8*)&dst16[base];
#pragma unroll
    for (int j = 0; j < 8; ++j) {
      int sn = (int)a[j] - range0;
      if ((unsigned)sn < (unsigned)RH) atomicAdd(&binsA[sn], 1);
      int dn = (int)b[j] - range0;
      if ((unsigned)dn < (unsigned)RH) atomicAdd(&binsB[dn], 1);
    }
  }
  __syncthreads();
  for (int i = t; i < RH; i += 256) {
    int n = range0 + i;
    if (n < N) {
      partialA[c * N + n] = binsA[i];
      partialB[c * N + n] = binsB[i];
    }
  }
}

// ---------- per-node chunk-prefix starts + cnt + norms + CSR sentinel padding ----------
// Pads each node's slot list to a multiple of 16 with sentinel node N (zero row),
// so the gather loop is branch-free with 4 loads in flight. Also zeroes h1n row N.
__global__ void k_starts(const int* __restrict__ partialA, const int* __restrict__ partialB,
                         int* __restrict__ starts, int* __restrict__ cnt,
                         float* __restrict__ norm_src, float* __restrict__ norm_dst,
                         unsigned short* __restrict__ esrc16,
                         unsigned short* __restrict__ h1n,
                         int N, int NCH) {
  int n = blockIdx.x * 256 + threadIdx.x;
  if (n < 16) {   // zero sentinel row h1n[N]
    us8 z = {0, 0, 0, 0, 0, 0, 0, 0};
    *(us8*)&h1n[(size_t)N * 128 + n * 8] = z;
  }
  if (n < N) {
    int dout = 0;
    for (int c = 0; c < NCH; ++c) dout += partialA[c * N + n];
    int run = n * CAP;
    for (int c = 0; c < NCH; ++c) {
      starts[c * N + n] = run;
      run += partialB[c * N + n];
    }
    int din = run - n * CAP;
    int cn = min(din, CAP);
    cnt[n] = cn;
    int cp = (cn + 15) & ~15;
    for (int pos = cn; pos < cp; ++pos) esrc16[n * CAP + pos] = (unsigned short)N;
    norm_src[n] = dout > 0 ? rsqrtf((float)dout) : 0.f;
    norm_dst[n] = din > 0 ? rsqrtf((float)din) : 0.f;
  }
}

// ---------- pass 2: scatter into fixed-cap CSR via LDS cursors ----------
__global__ __launch_bounds__(256) void k_scatter(const unsigned short* __restrict__ src16,
                                                 const unsigned short* __restrict__ dst16,
                                                 const int* __restrict__ starts,
                                                 unsigned short* __restrict__ esrc16,
                                                 int Epad, int N) {
  __shared__ int cur[RH];
  int range0 = blockIdx.x * RH;
  int c = blockIdx.y;
  int t = threadIdx.x;
  for (int i = t; i < RH; i += 256) {
    int n = range0 + i;
    cur[i] = (n < N) ? starts[c * N + n] : 0;
  }
  __syncthreads();
  int e0 = c * ECH, e1 = min(e0 + ECH, Epad);
  for (int base = e0 + t * 8; base < e1; base += 2048) {
    us8 a = *(const us8*)&src16[base];
    us8 b = *(const us8*)&dst16[base];
#pragma unroll
    for (int j = 0; j < 8; ++j) {
      int dn = (int)b[j] - range0;
      if ((unsigned)dn < (unsigned)RH) {
        int node = range0 + dn;
        int p = atomicAdd(&cur[dn], 1);
        if (p < (node + 1) * CAP) esrc16[p] = a[j];
      }
    }
  }
}

// ---------- GEMM1: 128x128 tile, BK=32, 8x8 register tile per thread ----------
__global__ __launch_bounds__(256) void k_gemm1(const float* __restrict__ x,
                                               const float* __restrict__ W1,
                                               const float* __restrict__ norm_src,
                                               unsigned short* __restrict__ h1n, int N) {
  __shared__ float xsT[BK][132];   // [k][row], pad -> conflict-free tr reads
  __shared__ float Wl[BK][132];    // [k][col]
  int row0 = blockIdx.x * 128;
  int tid = threadIdx.x;
  int tc = tid & 15;    // col group of 8
  int tr = tid >> 4;    // row group of 8
  float acc[8][8] = {{0.f}};

  for (int kb = 0; kb < 128; kb += BK) {
    __syncthreads();
#pragma unroll
    for (int it = 0; it < 4; ++it) {
      int i = tid + it * 256;
      int r = i >> 3, kq = i & 7;
      int grow = row0 + r;
      float4 v = make_float4(0.f, 0.f, 0.f, 0.f);
      if (grow < N) v = *(const float4*)&x[(size_t)grow * 128 + kb + kq * 4];
      xsT[kq * 4 + 0][r] = v.x;
      xsT[kq * 4 + 1][r] = v.y;
      xsT[kq * 4 + 2][r] = v.z;
      xsT[kq * 4 + 3][r] = v.w;
    }
#pragma unroll
    for (int it = 0; it < 4; ++it) {
      int i = tid + it * 256;
      int k = i >> 5, c4 = i & 31;
      *(float4*)&Wl[k][c4 * 4] = *(const float4*)&W1[(size_t)(kb + k) * 128 + c4 * 4];
    }
    __syncthreads();
#pragma unroll 2
    for (int k = 0; k < BK; ++k) {
      float4 xa = *(float4*)&xsT[k][tr * 8];
      float4 xb = *(float4*)&xsT[k][tr * 8 + 4];
      float4 wa = *(float4*)&Wl[k][tc * 8];
      float4 wb = *(float4*)&Wl[k][tc * 8 + 4];
      float xs[8] = {xa.x, xa.y, xa.z, xa.w, xb.x, xb.y, xb.z, xb.w};
      float ws[8] = {wa.x, wa.y, wa.z, wa.w, wb.x, wb.y, wb.z, wb.w};
#pragma unroll
      for (int i = 0; i < 8; ++i)
#pragma unroll
        for (int j = 0; j < 8; ++j) acc[i][j] += xs[i] * ws[j];
    }
  }
#pragma unroll
  for (int i = 0; i < 8; ++i) {
    int grow = row0 + tr * 8 + i;
    if (grow < N) {
      float ns = norm_src[grow];
      us8 o;
#pragma unroll
      for (int j = 0; j < 8; ++j) o[j] = f2bf(acc[i][j] * ns);
      *(us8*)&h1n[(size_t)grow * 128 + tc * 8] = o;
    }
  }
}

// ---------- fused layer-1 aggregation + ReLU + GEMM2 ----------
// One wave per dst node. Branch-free gather: sentinel-padded CSR, quads read
// their own eids (ushort4), 4 independent row loads in flight. W2 read from
// global only in the epilogue (no LDS, no loop-live registers).
__global__ __launch_bounds__(256) void k_agg1f(const unsigned short* __restrict__ h1n,
                                               const int* __restrict__ cnt,
                                               const unsigned short* __restrict__ esrc16,
                                               const float* __restrict__ norm_dst,
                                               const float* __restrict__ norm_src,
                                               const float* __restrict__ b1,
                                               const float* __restrict__ W2,
                                               float* __restrict__ h2n, int N) {
  int tid = threadIdx.x;
  int wid = (blockIdx.x * 256 + tid) >> 6;
  int lane = tid & 63;
  if (wid >= N) return;
  int q = lane >> 4;
  int fl = lane & 15;
  int cp = (cnt[wid] + 15) & ~15;
  int i0 = wid * CAP;
  int i1 = i0 + cp;
  float acc[8] = {0.f, 0.f, 0.f, 0.f, 0.f, 0.f, 0.f, 0.f};
  for (int i = i0; i < i1; i += 64) {
    int c64 = min(64, i1 - i);
    for (int t = 0; t < c64; t += 16) {
      int be = i + t + (q << 2);
      ushort4 ss = *(const ushort4*)&esrc16[be];   // 8B aligned (be % 4 == 0)
      us8 v0 = *(const us8*)&h1n[(size_t)ss.x * 128 + fl * 8];
      us8 v1 = *(const us8*)&h1n[(size_t)ss.y * 128 + fl * 8];
      us8 v2 = *(const us8*)&h1n[(size_t)ss.z * 128 + fl * 8];
      us8 v3 = *(const us8*)&h1n[(size_t)ss.w * 128 + fl * 8];
#pragma unroll
      for (int j = 0; j < 8; ++j)
        acc[j] += (bf2f(v0[j]) + bf2f(v1[j])) + (bf2f(v2[j]) + bf2f(v3[j]));
    }
  }
#pragma unroll
  for (int j = 0; j < 8; ++j) acc[j] += __shfl_down(acc[j], 32);
#pragma unroll
  for (int j = 0; j < 8; ++j) acc[j] += __shfl_down(acc[j], 16);
  if (lane < 16) {
    // lanes<16 hold the full h1 row (feats fl*8..fl*8+7)
    float nd = norm_dst[wid];
    float4 bb0 = *(const float4*)&b1[fl * 8];
    float4 bb1 = *(const float4*)&b1[fl * 8 + 4];
    float r[8];
    r[0] = fmaxf(acc[0] * nd + bb0.x, 0.f);
    r[1] = fmaxf(acc[1] * nd + bb0.y, 0.f);
    r[2] = fmaxf(acc[2] * nd + bb0.z, 0.f);
    r[3] = fmaxf(acc[3] * nd + bb0.w, 0.f);
    r[4] = fmaxf(acc[4] * nd + bb1.x, 0.f);
    r[5] = fmaxf(acc[5] * nd + bb1.y, 0.f);
    r[6] = fmaxf(acc[6] * nd + bb1.z, 0.f);
    r[7] = fmaxf(acc[7] * nd + bb1.w, 0.f);
    float4 pa = make_float4(0.f, 0.f, 0.f, 0.f);
    float4 pb = make_float4(0.f, 0.f, 0.f, 0.f);
#pragma unroll
    for (int jj = 0; jj < 8; ++jj) {
      float4 wa = *(const float4*)&W2[(fl * 8 + jj) * 8];
      float4 wb = *(const float4*)&W2[(fl * 8 + jj) * 8 + 4];
      pa.x += r[jj] * wa.x; pa.y += r[jj] * wa.y;
      pa.z += r[jj] * wa.z; pa.w += r[jj] * wa.w;
      pb.x += r[jj] * wb.x; pb.y += r[jj] * wb.y;
      pb.z += r[jj] * wb.z; pb.w += r[jj] * wb.w;
    }
    // tree-reduce over lanes 0..15
#pragma unroll
    for (int d = 8; d >= 1; d >>= 1) {
      pa.x += __shfl_down(pa.x, d); pa.y += __shfl_down(pa.y, d);
      pa.z += __shfl_down(pa.z, d); pa.w += __shfl_down(pa.w, d);
      pb.x += __shfl_down(pb.x, d); pb.y += __shfl_down(pb.y, d);
      pb.z += __shfl_down(pb.z, d); pb.w += __shfl_down(pb.w, d);
    }
    if (lane == 0) {
      float ns = norm_src[wid];
      pa.x *= ns; pa.y *= ns; pa.z *= ns; pa.w *= ns;
      pb.x *= ns; pb.y *= ns; pb.z *= ns; pb.w *= ns;
      *(float4*)&h2n[(size_t)wid * 8] = pa;
      *(float4*)&h2n[(size_t)wid * 8 + 4] = pb;
    }
  }
}

// ---------- layer-2 aggregation + mean-pool: LDS pre-reduction ----------
__global__ __launch_bounds__(256) void k_agg2pool(const float* __restrict__ h2n,
                                                  const int* __restrict__ cnt,
                                                  const unsigned short* __restrict__ esrc16,
                                                  const float* __restrict__ norm_dst,
                                                  const float* __restrict__ b2,
                                                  const int* __restrict__ gids,
                                                  float* __restrict__ gsum, int N) {
  __shared__ float bins[16 * 8];
  __shared__ int sg0;
  int tid = threadIdx.x;
  if (tid < 128) bins[tid] = 0.f;
  int base = blockIdx.x * 32;
  if (tid == 0) sg0 = gids[min(base, N - 1)];
  __syncthreads();
  int node = base + (tid >> 3);
  int j = tid & 7;
  if (node < N) {
    int i0 = node * CAP;
    int i1 = i0 + cnt[node];
    float acc = 0.f;
    for (int i = i0; i < i1; i += 8) {
      int c8 = min(8, i1 - i);
      int eid = (i + j < i1) ? (int)esrc16[i + j] : 0;
      for (int t = 0; t < c8; ++t) {
        int s = __shfl(eid, t, 8);
        acc += h2n[s * 8 + j];
      }
    }
    float r = acc * norm_dst[node] + b2[j];
    int delta = gids[node] - sg0;
    if (delta < 16) atomicAdd(&bins[delta * 8 + j], r);
    else atomicAdd(&gsum[gids[node] * 8 + j], r);
  }
  __syncthreads();
  if (tid < 128) {
    float v = bins[tid];
    if (v != 0.f) atomicAdd(&gsum[(sg0 + (tid >> 3)) * 8 + (tid & 7)], v);
  }
}

// ---------- final ----------
__global__ void k_final(const float* __restrict__ gsum, const int* __restrict__ gids,
                        float* __restrict__ out, int NG, int N) {
  int i = blockIdx.x * 256 + threadIdx.x;
  if (i < NG * F2) {
    int g = i >> 3;
    int lo = 0, hi = N;
    while (lo < hi) { int m = (lo + hi) >> 1; if (gids[m] < g) lo = m + 1; else hi = m; }
    int lb = lo;
    lo = 0; hi = N;
    while (lo < hi) { int m = (lo + hi) >> 1; if (gids[m] <= g) lo = m + 1; else hi = m; }
    int cnt = lo - lb;
    out[i] = gsum[i] / fmaxf((float)cnt, 1.f);
  }
}

extern "C" void kernel_launch(void* const* d_in, const int* in_sizes, int n_in,
                              void* d_out, int out_size, void* d_ws, size_t ws_size,
                              hipStream_t stream) {
  const float* x  = (const float*)d_in[0];
  const float* W1 = (const float*)d_in[1];
  const float* b1 = (const float*)d_in[2];
  const float* W2 = (const float*)d_in[3];
  const float* b2 = (const float*)d_in[4];
  const int* src  = (const int*)d_in[5];
  const int* dst  = (const int*)d_in[6];
  const int* gids = (const int*)d_in[7];
  int N = in_sizes[0] / F1;
  int E = in_sizes[5];
  int NG = out_size / F2;
  float* out = (float*)d_out;

  int Epad = (E + 2047) & ~2047;            // multiple of 256*8
  int NR  = (N + RH - 1) / RH;              // node ranges
  int NCH = (Epad + ECH - 1) / ECH;         // edge chunks

  char* p = (char*)d_ws;
  auto alloc = [&](size_t bytes) -> void* {
    void* r = (void*)p;
    p += (bytes + 255) & ~(size_t)255;
    return r;
  };
  float* gsum    = (float*)alloc((size_t)NG * F2 * 4);       // zeroed
  size_t zero_bytes = (size_t)((char*)p - (char*)gsum);
  unsigned short* src16 = (unsigned short*)alloc((size_t)Epad * 2);
  unsigned short* dst16 = (unsigned short*)alloc((size_t)Epad * 2);
  int* cnt       = (int*)alloc((size_t)N * 4);
  float* norm_src = (float*)alloc((size_t)N * 4);
  float* norm_dst = (float*)alloc((size_t)N * 4);
  unsigned short* esrc16 = (unsigned short*)alloc((size_t)N * CAP * 2);
  unsigned short* h1n = (unsigned short*)alloc((size_t)(N + 1) * F1 * 2);  // +1 sentinel row
  float* h2n     = (float*)alloc((size_t)N * F2 * 4);
  int* partialA  = (int*)alloc((size_t)NCH * N * 4);
  int* partialB  = (int*)alloc((size_t)NCH * N * 4);
  int* starts    = (int*)alloc((size_t)NCH * N * 4);
  (void)ws_size; (void)n_in;

  hipMemsetAsync(gsum, 0, zero_bytes, stream);

  k_pack<<<(Epad + 255) / 256, 256, 0, stream>>>(src, dst, src16, dst16, E, Epad);
  k_hist<<<dim3(NR, NCH), 256, 0, stream>>>(src16, dst16, partialA, partialB, Epad, N);
  k_starts<<<(N + 255) / 256, 256, 0, stream>>>(partialA, partialB, starts, cnt,
                                                norm_src, norm_dst, esrc16, h1n, N, NCH);
  k_scatter<<<dim3(NR, NCH), 256, 0, stream>>>(src16, dst16, starts, esrc16, Epad, N);
  k_gemm1<<<(N + 127) / 128, 256, 0, stream>>>(x, W1, norm_src, h1n, N);
  k_agg1f<<<(N + 3) / 4, 256, 0, stream>>>(h1n, cnt, esrc16, norm_dst, norm_src, b1, W2, h2n, N);
  k_agg2pool<<<((N * 8 + 255) / 256), 256, 0, stream>>>(h2n, cnt, esrc16, norm_dst, b2, gids, gsum, N);
  k_final<<<(NG * F2 + 255) / 256, 256, 0, stream>>>(gsum, gids, out, NG, N);
}

// Round 11
// 244.023 us; speedup vs baseline: 1.3192x; 1.0616x over previous
//
#include <hip/hip_runtime.h>

#define F1 128
#define F2 8
#define CAP 64       // fixed CSR capacity per node (deg ~ Poisson(16); P(>64) ~ 1e-20)
#define RH 8192      // nodes per range (32 KB LDS bins)
#define ECH 16384    // edges per chunk (multiple of 2048)
#define BK 32        // gemm1 K-chunk

typedef unsigned short us8 __attribute__((ext_vector_type(8)));

__device__ inline unsigned short f2bf(float f) {
  unsigned u = __float_as_uint(f);
  u += 0x7FFF + ((u >> 16) & 1);   // round-to-nearest-even
  return (unsigned short)(u >> 16);
}
__device__ inline float bf2f(unsigned short h) {
  return __uint_as_float(((unsigned)h) << 16);
}

// ---------- pack indices to ushort (N < 65536), pad with 0xFFFF ----------
__global__ void k_pack(const int* __restrict__ src, const int* __restrict__ dst,
                       unsigned short* __restrict__ src16, unsigned short* __restrict__ dst16,
                       int E, int Epad) {
  int e = blockIdx.x * 256 + threadIdx.x;
  if (e < Epad) {
    src16[e] = (e < E) ? (unsigned short)src[e] : (unsigned short)0xFFFF;
    dst16[e] = (e < E) ? (unsigned short)dst[e] : (unsigned short)0xFFFF;
  }
}

// ---------- pass 1: per-(range,chunk) histograms of src AND dst, LDS-only atomics ----------
__global__ __launch_bounds__(256) void k_hist(const unsigned short* __restrict__ src16,
                                              const unsigned short* __restrict__ dst16,
                                              int* __restrict__ partialA,
                                              int* __restrict__ partialB,
                                              int Epad, int N) {
  __shared__ int binsA[RH];
  __shared__ int binsB[RH];
  int range0 = blockIdx.x * RH;
  int c = blockIdx.y;
  int t = threadIdx.x;
  for (int i = t; i < RH; i += 256) { binsA[i] = 0; binsB[i] = 0; }
  __syncthreads();
  int e0 = c * ECH, e1 = min(e0 + ECH, Epad);
  for (int base = e0 + t * 8; base < e1; base += 2048) {
    us8 a = *(const us8*)&src16[base];
    us8 b = *(const us8*)&dst16[base];
#pragma unroll
    for (int j = 0; j < 8; ++j) {
      int sn = (int)a[j] - range0;
      if ((unsigned)sn < (unsigned)RH) atomicAdd(&binsA[sn], 1);
      int dn = (int)b[j] - range0;
      if ((unsigned)dn < (unsigned)RH) atomicAdd(&binsB[dn], 1);
    }
  }
  __syncthreads();
  for (int i = t; i < RH; i += 256) {
    int n = range0 + i;
    if (n < N) {
      partialA[c * N + n] = binsA[i];
      partialB[c * N + n] = binsB[i];
    }
  }
}

// ---------- per-node chunk-prefix starts + cnt + norms + CSR sentinel padding ----------
// Pads each node's slot list to a multiple of 16 with sentinel node N (zero rows
// in h1n AND h2n), so gather loops are branch-free with multiple loads in flight.
__global__ void k_starts(const int* __restrict__ partialA, const int* __restrict__ partialB,
                         int* __restrict__ starts, int* __restrict__ cnt,
                         float* __restrict__ norm_src, float* __restrict__ norm_dst,
                         unsigned short* __restrict__ esrc16,
                         unsigned short* __restrict__ h1n,
                         float* __restrict__ h2n,
                         int N, int NCH) {
  int n = blockIdx.x * 256 + threadIdx.x;
  if (n < 16) {   // zero sentinel row h1n[N]
    us8 z = {0, 0, 0, 0, 0, 0, 0, 0};
    *(us8*)&h1n[(size_t)N * 128 + n * 8] = z;
  }
  if (n < 8) h2n[(size_t)N * 8 + n] = 0.f;   // zero sentinel row h2n[N]
  if (n < N) {
    int dout = 0;
    for (int c = 0; c < NCH; ++c) dout += partialA[c * N + n];
    int run = n * CAP;
    for (int c = 0; c < NCH; ++c) {
      starts[c * N + n] = run;
      run += partialB[c * N + n];
    }
    int din = run - n * CAP;
    int cn = min(din, CAP);
    cnt[n] = cn;
    int cp = (cn + 15) & ~15;
    for (int pos = cn; pos < cp; ++pos) esrc16[n * CAP + pos] = (unsigned short)N;
    norm_src[n] = dout > 0 ? rsqrtf((float)dout) : 0.f;
    norm_dst[n] = din > 0 ? rsqrtf((float)din) : 0.f;
  }
}

// ---------- pass 2: scatter into fixed-cap CSR via LDS cursors ----------
__global__ __launch_bounds__(256) void k_scatter(const unsigned short* __restrict__ src16,
                                                 const unsigned short* __restrict__ dst16,
                                                 const int* __restrict__ starts,
                                                 unsigned short* __restrict__ esrc16,
                                                 int Epad, int N) {
  __shared__ int cur[RH];
  int range0 = blockIdx.x * RH;
  int c = blockIdx.y;
  int t = threadIdx.x;
  for (int i = t; i < RH; i += 256) {
    int n = range0 + i;
    cur[i] = (n < N) ? starts[c * N + n] : 0;
  }
  __syncthreads();
  int e0 = c * ECH, e1 = min(e0 + ECH, Epad);
  for (int base = e0 + t * 8; base < e1; base += 2048) {
    us8 a = *(const us8*)&src16[base];
    us8 b = *(const us8*)&dst16[base];
#pragma unroll
    for (int j = 0; j < 8; ++j) {
      int dn = (int)b[j] - range0;
      if ((unsigned)dn < (unsigned)RH) {
        int node = range0 + dn;
        int p = atomicAdd(&cur[dn], 1);
        if (p < (node + 1) * CAP) esrc16[p] = a[j];
      }
    }
  }
}

// ---------- GEMM1: 128x128 tile, BK=32, 8x8 register tile per thread ----------
__global__ __launch_bounds__(256) void k_gemm1(const float* __restrict__ x,
                                               const float* __restrict__ W1,
                                               const float* __restrict__ norm_src,
                                               unsigned short* __restrict__ h1n, int N) {
  __shared__ float xsT[BK][132];   // [k][row], pad -> conflict-free tr reads
  __shared__ float Wl[BK][132];    // [k][col]
  int row0 = blockIdx.x * 128;
  int tid = threadIdx.x;
  int tc = tid & 15;    // col group of 8
  int tr = tid >> 4;    // row group of 8
  float acc[8][8] = {{0.f}};

  for (int kb = 0; kb < 128; kb += BK) {
    __syncthreads();
#pragma unroll
    for (int it = 0; it < 4; ++it) {
      int i = tid + it * 256;
      int r = i >> 3, kq = i & 7;
      int grow = row0 + r;
      float4 v = make_float4(0.f, 0.f, 0.f, 0.f);
      if (grow < N) v = *(const float4*)&x[(size_t)grow * 128 + kb + kq * 4];
      xsT[kq * 4 + 0][r] = v.x;
      xsT[kq * 4 + 1][r] = v.y;
      xsT[kq * 4 + 2][r] = v.z;
      xsT[kq * 4 + 3][r] = v.w;
    }
#pragma unroll
    for (int it = 0; it < 4; ++it) {
      int i = tid + it * 256;
      int k = i >> 5, c4 = i & 31;
      *(float4*)&Wl[k][c4 * 4] = *(const float4*)&W1[(size_t)(kb + k) * 128 + c4 * 4];
    }
    __syncthreads();
#pragma unroll 2
    for (int k = 0; k < BK; ++k) {
      float4 xa = *(float4*)&xsT[k][tr * 8];
      float4 xb = *(float4*)&xsT[k][tr * 8 + 4];
      float4 wa = *(float4*)&Wl[k][tc * 8];
      float4 wb = *(float4*)&Wl[k][tc * 8 + 4];
      float xs[8] = {xa.x, xa.y, xa.z, xa.w, xb.x, xb.y, xb.z, xb.w};
      float ws[8] = {wa.x, wa.y, wa.z, wa.w, wb.x, wb.y, wb.z, wb.w};
#pragma unroll
      for (int i = 0; i < 8; ++i)
#pragma unroll
        for (int j = 0; j < 8; ++j) acc[i][j] += xs[i] * ws[j];
    }
  }
#pragma unroll
  for (int i = 0; i < 8; ++i) {
    int grow = row0 + tr * 8 + i;
    if (grow < N) {
      float ns = norm_src[grow];
      us8 o;
#pragma unroll
      for (int j = 0; j < 8; ++j) o[j] = f2bf(acc[i][j] * ns);
      *(us8*)&h1n[(size_t)grow * 128 + tc * 8] = o;
    }
  }
}

// ---------- fused layer-1 aggregation + ReLU + GEMM2: 4 nodes per wave ----------
// Each 16-lane group owns one node end-to-end: lane fl reads feats fl*8..fl*8+7
// of every gathered row -> acc complete per lane, NO cross-lane fold. 4 groups
// x 4 rows = 16 independent row loads in flight per wave. Epilogue all-lane.
__global__ __launch_bounds__(256) void k_agg1f(const unsigned short* __restrict__ h1n,
                                               const int* __restrict__ cnt,
                                               const unsigned short* __restrict__ esrc16,
                                               const float* __restrict__ norm_dst,
                                               const float* __restrict__ norm_src,
                                               const float* __restrict__ b1,
                                               const float* __restrict__ W2,
                                               float* __restrict__ h2n, int N) {
  int tid = threadIdx.x;
  int lane = tid & 63;
  int g = lane >> 4;          // group = node within wave
  int fl = lane & 15;         // feature slice
  int node = (blockIdx.x * 256 + tid - lane) / 16 + g;  // wave_id*4 + g
  if (node >= N) return;
  int cp = (cnt[node] + 15) & ~15;
  int i0 = node * CAP;
  float acc[8] = {0.f, 0.f, 0.f, 0.f, 0.f, 0.f, 0.f, 0.f};
  for (int i = 0; i < cp; i += 16) {
#pragma unroll
    for (int t4 = 0; t4 < 16; t4 += 4) {
      ushort4 ss = *(const ushort4*)&esrc16[i0 + i + t4];   // group-uniform broadcast
      us8 v0 = *(const us8*)&h1n[(size_t)ss.x * 128 + fl * 8];
      us8 v1 = *(const us8*)&h1n[(size_t)ss.y * 128 + fl * 8];
      us8 v2 = *(const us8*)&h1n[(size_t)ss.z * 128 + fl * 8];
      us8 v3 = *(const us8*)&h1n[(size_t)ss.w * 128 + fl * 8];
#pragma unroll
      for (int j = 0; j < 8; ++j)
        acc[j] += (bf2f(v0[j]) + bf2f(v1[j])) + (bf2f(v2[j]) + bf2f(v3[j]));
    }
  }
  // epilogue: all 64 lanes active (4 nodes concurrently)
  float nd = norm_dst[node];
  float4 bb0 = *(const float4*)&b1[fl * 8];
  float4 bb1 = *(const float4*)&b1[fl * 8 + 4];
  float r[8];
  r[0] = fmaxf(acc[0] * nd + bb0.x, 0.f);
  r[1] = fmaxf(acc[1] * nd + bb0.y, 0.f);
  r[2] = fmaxf(acc[2] * nd + bb0.z, 0.f);
  r[3] = fmaxf(acc[3] * nd + bb0.w, 0.f);
  r[4] = fmaxf(acc[4] * nd + bb1.x, 0.f);
  r[5] = fmaxf(acc[5] * nd + bb1.y, 0.f);
  r[6] = fmaxf(acc[6] * nd + bb1.z, 0.f);
  r[7] = fmaxf(acc[7] * nd + bb1.w, 0.f);
  float4 pa = make_float4(0.f, 0.f, 0.f, 0.f);
  float4 pb = make_float4(0.f, 0.f, 0.f, 0.f);
#pragma unroll
  for (int jj = 0; jj < 8; ++jj) {
    float4 wa = *(const float4*)&W2[(fl * 8 + jj) * 8];
    float4 wb = *(const float4*)&W2[(fl * 8 + jj) * 8 + 4];
    pa.x += r[jj] * wa.x; pa.y += r[jj] * wa.y;
    pa.z += r[jj] * wa.z; pa.w += r[jj] * wa.w;
    pb.x += r[jj] * wb.x; pb.y += r[jj] * wb.y;
    pb.z += r[jj] * wb.z; pb.w += r[jj] * wb.w;
  }
  // group-local tree-reduce (d<16 stays inside the 16-lane group)
#pragma unroll
  for (int d = 8; d >= 1; d >>= 1) {
    pa.x += __shfl_down(pa.x, d); pa.y += __shfl_down(pa.y, d);
    pa.z += __shfl_down(pa.z, d); pa.w += __shfl_down(pa.w, d);
    pb.x += __shfl_down(pb.x, d); pb.y += __shfl_down(pb.y, d);
    pb.z += __shfl_down(pb.z, d); pb.w += __shfl_down(pb.w, d);
  }
  if (fl == 0) {
    float ns = norm_src[node];
    pa.x *= ns; pa.y *= ns; pa.z *= ns; pa.w *= ns;
    pb.x *= ns; pb.y *= ns; pb.z *= ns; pb.w *= ns;
    *(float4*)&h2n[(size_t)node * 8] = pa;
    *(float4*)&h2n[(size_t)node * 8 + 4] = pb;
  }
}

// ---------- layer-2 aggregation + mean-pool: sentinel-padded, 4 loads in flight ----------
__global__ __launch_bounds__(256) void k_agg2pool(const float* __restrict__ h2n,
                                                  const int* __restrict__ cnt,
                                                  const unsigned short* __restrict__ esrc16,
                                                  const float* __restrict__ norm_dst,
                                                  const float* __restrict__ b2,
                                                  const int* __restrict__ gids,
                                                  float* __restrict__ gsum, int N) {
  __shared__ float bins[16 * 8];
  __shared__ int sg0;
  int tid = threadIdx.x;
  if (tid < 128) bins[tid] = 0.f;
  int base = blockIdx.x * 32;
  if (tid == 0) sg0 = gids[min(base, N - 1)];
  __syncthreads();
  int node = base + (tid >> 3);
  int j = tid & 7;
  if (node < N) {
    int cp = (cnt[node] + 15) & ~15;
    int i0 = node * CAP;
    float acc = 0.f;
    for (int i = 0; i < cp; i += 4) {
      ushort4 ss = *(const ushort4*)&esrc16[i0 + i];   // group-uniform broadcast
      acc += (h2n[(size_t)ss.x * 8 + j] + h2n[(size_t)ss.y * 8 + j]) +
             (h2n[(size_t)ss.z * 8 + j] + h2n[(size_t)ss.w * 8 + j]);
    }
    float r = acc * norm_dst[node] + b2[j];
    int delta = gids[node] - sg0;
    if (delta < 16) atomicAdd(&bins[delta * 8 + j], r);
    else atomicAdd(&gsum[gids[node] * 8 + j], r);
  }
  __syncthreads();
  if (tid < 128) {
    float v = bins[tid];
    if (v != 0.f) atomicAdd(&gsum[(sg0 + (tid >> 3)) * 8 + (tid & 7)], v);
  }
}

// ---------- final ----------
__global__ void k_final(const float* __restrict__ gsum, const int* __restrict__ gids,
                        float* __restrict__ out, int NG, int N) {
  int i = blockIdx.x * 256 + threadIdx.x;
  if (i < NG * F2) {
    int g = i >> 3;
    int lo = 0, hi = N;
    while (lo < hi) { int m = (lo + hi) >> 1; if (gids[m] < g) lo = m + 1; else hi = m; }
    int lb = lo;
    lo = 0; hi = N;
    while (lo < hi) { int m = (lo + hi) >> 1; if (gids[m] <= g) lo = m + 1; else hi = m; }
    int cnt = lo - lb;
    out[i] = gsum[i] / fmaxf((float)cnt, 1.f);
  }
}

extern "C" void kernel_launch(void* const* d_in, const int* in_sizes, int n_in,
                              void* d_out, int out_size, void* d_ws, size_t ws_size,
                              hipStream_t stream) {
  const float* x  = (const float*)d_in[0];
  const float* W1 = (const float*)d_in[1];
  const float* b1 = (const float*)d_in[2];
  const float* W2 = (const float*)d_in[3];
  const float* b2 = (const float*)d_in[4];
  const int* src  = (const int*)d_in[5];
  const int* dst  = (const int*)d_in[6];
  const int* gids = (const int*)d_in[7];
  int N = in_sizes[0] / F1;
  int E = in_sizes[5];
  int NG = out_size / F2;
  float* out = (float*)d_out;

  int Epad = (E + 2047) & ~2047;            // multiple of 256*8
  int NR  = (N + RH - 1) / RH;              // node ranges
  int NCH = (Epad + ECH - 1) / ECH;         // edge chunks

  char* p = (char*)d_ws;
  auto alloc = [&](size_t bytes) -> void* {
    void* r = (void*)p;
    p += (bytes + 255) & ~(size_t)255;
    return r;
  };
  float* gsum    = (float*)alloc((size_t)NG * F2 * 4);       // zeroed
  size_t zero_bytes = (size_t)((char*)p - (char*)gsum);
  unsigned short* src16 = (unsigned short*)alloc((size_t)Epad * 2);
  unsigned short* dst16 = (unsigned short*)alloc((size_t)Epad * 2);
  int* cnt       = (int*)alloc((size_t)N * 4);
  float* norm_src = (float*)alloc((size_t)N * 4);
  float* norm_dst = (float*)alloc((size_t)N * 4);
  unsigned short* esrc16 = (unsigned short*)alloc((size_t)N * CAP * 2);
  unsigned short* h1n = (unsigned short*)alloc((size_t)(N + 1) * F1 * 2);  // +1 sentinel row
  float* h2n     = (float*)alloc((size_t)(N + 1) * F2 * 4);                // +1 sentinel row
  int* partialA  = (int*)alloc((size_t)NCH * N * 4);
  int* partialB  = (int*)alloc((size_t)NCH * N * 4);
  int* starts    = (int*)alloc((size_t)NCH * N * 4);
  (void)ws_size; (void)n_in;

  hipMemsetAsync(gsum, 0, zero_bytes, stream);

  k_pack<<<(Epad + 255) / 256, 256, 0, stream>>>(src, dst, src16, dst16, E, Epad);
  k_hist<<<dim3(NR, NCH), 256, 0, stream>>>(src16, dst16, partialA, partialB, Epad, N);
  k_starts<<<(N + 255) / 256, 256, 0, stream>>>(partialA, partialB, starts, cnt,
                                                norm_src, norm_dst, esrc16, h1n, h2n, N, NCH);
  k_scatter<<<dim3(NR, NCH), 256, 0, stream>>>(src16, dst16, starts, esrc16, Epad, N);
  k_gemm1<<<(N + 127) / 128, 256, 0, stream>>>(x, W1, norm_src, h1n, N);
  k_agg1f<<<(N + 15) / 16, 256, 0, stream>>>(h1n, cnt, esrc16, norm_dst, norm_src, b1, W2, h2n, N);
  k_agg2pool<<<((N * 8 + 255) / 256), 256, 0, stream>>>(h2n, cnt, esrc16, norm_dst, b2, gids, gsum, N);
  k_final<<<(NG * F2 + 255) / 256, 256, 0, stream>>>(gsum, gids, out, NG, N);
}

// Round 12
// 227.216 us; speedup vs baseline: 1.4168x; 1.0740x over previous
//
#include <hip/hip_runtime.h>

#define F1 128
#define F2 8
#define CAP 64       // fixed CSR capacity per node (deg ~ Poisson(16); P(>64) ~ 1e-20)
#define RH 8192      // nodes per range (32 KB LDS bins)
#define ECH 16384    // edges per chunk (multiple of 2048)
#define BK 32        // gemm1 K-chunk

typedef unsigned short us8 __attribute__((ext_vector_type(8)));

__device__ inline unsigned short f2bf(float f) {
  unsigned u = __float_as_uint(f);
  u += 0x7FFF + ((u >> 16) & 1);   // round-to-nearest-even
  return (unsigned short)(u >> 16);
}
__device__ inline float bf2f(unsigned short h) {
  return __uint_as_float(((unsigned)h) << 16);
}

// ---------- pass 1: histograms of src AND dst + packed ushort emission ----------
// Reads int src/dst directly (absorbs old k_pack); blocks with blockIdx.x==0
// additionally write src16/dst16 (incl. 0xFFFF padding to Epad).
__global__ __launch_bounds__(256) void k_hist(const int* __restrict__ src,
                                              const int* __restrict__ dst,
                                              unsigned short* __restrict__ src16,
                                              unsigned short* __restrict__ dst16,
                                              int* __restrict__ partialA,
                                              int* __restrict__ partialB,
                                              int Epad, int E, int N) {
  __shared__ int binsA[RH];
  __shared__ int binsB[RH];
  int range0 = blockIdx.x * RH;
  int c = blockIdx.y;
  int t = threadIdx.x;
  bool writer = (blockIdx.x == 0);
  for (int i = t; i < RH; i += 256) { binsA[i] = 0; binsB[i] = 0; }
  __syncthreads();
  int e0 = c * ECH, e1 = min(e0 + ECH, Epad);
  for (int base = e0 + t * 4; base < e1; base += 1024) {
    int4 a, b;
    if (base + 4 <= E) {
      a = *(const int4*)&src[base];
      b = *(const int4*)&dst[base];
    } else {
      a.x = (base + 0 < E) ? src[base + 0] : -1;
      a.y = (base + 1 < E) ? src[base + 1] : -1;
      a.z = (base + 2 < E) ? src[base + 2] : -1;
      a.w = (base + 3 < E) ? src[base + 3] : -1;
      b.x = (base + 0 < E) ? dst[base + 0] : -1;
      b.y = (base + 1 < E) ? dst[base + 1] : -1;
      b.z = (base + 2 < E) ? dst[base + 2] : -1;
      b.w = (base + 3 < E) ? dst[base + 3] : -1;
    }
    int av[4] = {a.x, a.y, a.z, a.w};
    int bv[4] = {b.x, b.y, b.z, b.w};
#pragma unroll
    for (int j = 0; j < 4; ++j) {
      int sn = av[j] - range0;
      if (av[j] >= 0 && (unsigned)sn < (unsigned)RH) atomicAdd(&binsA[sn], 1);
      int dn = bv[j] - range0;
      if (bv[j] >= 0 && (unsigned)dn < (unsigned)RH) atomicAdd(&binsB[dn], 1);
    }
    if (writer) {
      ushort4 sa, sb;
      sa.x = av[0] >= 0 ? (unsigned short)av[0] : 0xFFFF;
      sa.y = av[1] >= 0 ? (unsigned short)av[1] : 0xFFFF;
      sa.z = av[2] >= 0 ? (unsigned short)av[2] : 0xFFFF;
      sa.w = av[3] >= 0 ? (unsigned short)av[3] : 0xFFFF;
      sb.x = bv[0] >= 0 ? (unsigned short)bv[0] : 0xFFFF;
      sb.y = bv[1] >= 0 ? (unsigned short)bv[1] : 0xFFFF;
      sb.z = bv[2] >= 0 ? (unsigned short)bv[2] : 0xFFFF;
      sb.w = bv[3] >= 0 ? (unsigned short)bv[3] : 0xFFFF;
      *(ushort4*)&src16[base] = sa;
      *(ushort4*)&dst16[base] = sb;
    }
  }
  __syncthreads();
  for (int i = t; i < RH; i += 256) {
    int n = range0 + i;
    if (n < N) {
      partialA[c * N + n] = binsA[i];
      partialB[c * N + n] = binsB[i];
    }
  }
}

// ---------- starts + cnt + norms + sentinel pad + gsum zero (fused housekeeping) ----------
__global__ void k_starts(const int* __restrict__ partialA, const int* __restrict__ partialB,
                         int* __restrict__ starts, int* __restrict__ cnt,
                         float* __restrict__ norm_src, float* __restrict__ norm_dst,
                         unsigned short* __restrict__ esrc16,
                         unsigned short* __restrict__ h1n,
                         float* __restrict__ h2n,
                         float* __restrict__ gsum,
                         int N, int NCH, int NGF) {
  int n = blockIdx.x * 256 + threadIdx.x;
  if (n < NGF) gsum[n] = 0.f;               // replaces hipMemsetAsync
  if (n < 16) {                             // zero sentinel row h1n[N]
    us8 z = {0, 0, 0, 0, 0, 0, 0, 0};
    *(us8*)&h1n[(size_t)N * 128 + n * 8] = z;
  }
  if (n < 8) h2n[(size_t)N * 8 + n] = 0.f;  // zero sentinel row h2n[N]
  if (n < N) {
    int dout = 0;
#pragma unroll 8
    for (int c = 0; c < NCH; ++c) dout += partialA[c * N + n];
    int run = n * CAP;
#pragma unroll 8
    for (int c = 0; c < NCH; ++c) {
      starts[c * N + n] = run;
      run += partialB[c * N + n];
    }
    int din = run - n * CAP;
    int cn = min(din, CAP);
    cnt[n] = cn;
    int cp = (cn + 15) & ~15;
    for (int pos = cn; pos < cp; ++pos) esrc16[n * CAP + pos] = (unsigned short)N;
    norm_src[n] = dout > 0 ? rsqrtf((float)dout) : 0.f;
    norm_dst[n] = din > 0 ? rsqrtf((float)din) : 0.f;
  }
}

// ---------- pass 2: scatter into fixed-cap CSR via LDS cursors ----------
__global__ __launch_bounds__(256) void k_scatter(const unsigned short* __restrict__ src16,
                                                 const unsigned short* __restrict__ dst16,
                                                 const int* __restrict__ starts,
                                                 unsigned short* __restrict__ esrc16,
                                                 int Epad, int N) {
  __shared__ int cur[RH];
  int range0 = blockIdx.x * RH;
  int c = blockIdx.y;
  int t = threadIdx.x;
  for (int i = t; i < RH; i += 256) {
    int n = range0 + i;
    cur[i] = (n < N) ? starts[c * N + n] : 0;
  }
  __syncthreads();
  int e0 = c * ECH, e1 = min(e0 + ECH, Epad);
  for (int base = e0 + t * 8; base < e1; base += 2048) {
    us8 a = *(const us8*)&src16[base];
    us8 b = *(const us8*)&dst16[base];
#pragma unroll
    for (int j = 0; j < 8; ++j) {
      int dn = (int)b[j] - range0;
      if ((unsigned)dn < (unsigned)RH) {
        int node = range0 + dn;
        int p = atomicAdd(&cur[dn], 1);
        if (p < (node + 1) * CAP) esrc16[p] = a[j];
      }
    }
  }
}

// ---------- GEMM1: 128x128 tile, BK=32, 8x8 register tile per thread ----------
__global__ __launch_bounds__(256) void k_gemm1(const float* __restrict__ x,
                                               const float* __restrict__ W1,
                                               const float* __restrict__ norm_src,
                                               unsigned short* __restrict__ h1n, int N) {
  __shared__ float xsT[BK][132];   // [k][row], pad -> conflict-free tr reads
  __shared__ float Wl[BK][132];    // [k][col]
  int row0 = blockIdx.x * 128;
  int tid = threadIdx.x;
  int tc = tid & 15;    // col group of 8
  int tr = tid >> 4;    // row group of 8
  float acc[8][8] = {{0.f}};

  for (int kb = 0; kb < 128; kb += BK) {
    __syncthreads();
#pragma unroll
    for (int it = 0; it < 4; ++it) {
      int i = tid + it * 256;
      int r = i >> 3, kq = i & 7;
      int grow = row0 + r;
      float4 v = make_float4(0.f, 0.f, 0.f, 0.f);
      if (grow < N) v = *(const float4*)&x[(size_t)grow * 128 + kb + kq * 4];
      xsT[kq * 4 + 0][r] = v.x;
      xsT[kq * 4 + 1][r] = v.y;
      xsT[kq * 4 + 2][r] = v.z;
      xsT[kq * 4 + 3][r] = v.w;
    }
#pragma unroll
    for (int it = 0; it < 4; ++it) {
      int i = tid + it * 256;
      int k = i >> 5, c4 = i & 31;
      *(float4*)&Wl[k][c4 * 4] = *(const float4*)&W1[(size_t)(kb + k) * 128 + c4 * 4];
    }
    __syncthreads();
#pragma unroll 2
    for (int k = 0; k < BK; ++k) {
      float4 xa = *(float4*)&xsT[k][tr * 8];
      float4 xb = *(float4*)&xsT[k][tr * 8 + 4];
      float4 wa = *(float4*)&Wl[k][tc * 8];
      float4 wb = *(float4*)&Wl[k][tc * 8 + 4];
      float xs[8] = {xa.x, xa.y, xa.z, xa.w, xb.x, xb.y, xb.z, xb.w};
      float ws[8] = {wa.x, wa.y, wa.z, wa.w, wb.x, wb.y, wb.z, wb.w};
#pragma unroll
      for (int i = 0; i < 8; ++i)
#pragma unroll
        for (int j = 0; j < 8; ++j) acc[i][j] += xs[i] * ws[j];
    }
  }
#pragma unroll
  for (int i = 0; i < 8; ++i) {
    int grow = row0 + tr * 8 + i;
    if (grow < N) {
      float ns = norm_src[grow];
      us8 o;
#pragma unroll
      for (int j = 0; j < 8; ++j) o[j] = f2bf(acc[i][j] * ns);
      *(us8*)&h1n[(size_t)grow * 128 + tc * 8] = o;
    }
  }
}

// ---------- fused layer-1 aggregation + ReLU + GEMM2: 4 nodes/wave, reg-resident eids ----------
// Lane fl preloads slots fl*4..fl*4+3 of its node's list (one ushort4) -> whole
// 64-slot list lives in 2 VGPRs/lane. Batch loop broadcasts eids via __shfl
// (register, no memory) -> ONE memory round-trip (the 16 row loads) per batch.
__global__ __launch_bounds__(256) void k_agg1f(const unsigned short* __restrict__ h1n,
                                               const int* __restrict__ cnt,
                                               const unsigned short* __restrict__ esrc16,
                                               const float* __restrict__ norm_dst,
                                               const float* __restrict__ norm_src,
                                               const float* __restrict__ b1,
                                               const float* __restrict__ W2,
                                               float* __restrict__ h2n, int N) {
  int tid = threadIdx.x;
  int lane = tid & 63;
  int g = lane >> 4;          // group = node within wave
  int fl = lane & 15;         // feature slice / owned slot quad
  int node = (blockIdx.x * 256 + tid - lane) / 16 + g;
  if (node >= N) return;
  int nb = (cnt[node] + 15) >> 4;                     // batches of 16 edges
  size_t i0 = (size_t)node * CAP;
  ushort4 myss = *(const ushort4*)&esrc16[i0 + fl * 4];  // slots fl*4..fl*4+3
  unsigned u0 = (unsigned)myss.x | ((unsigned)myss.y << 16);
  unsigned u1 = (unsigned)myss.z | ((unsigned)myss.w << 16);
  int gbase = g << 4;
  float acc[8] = {0.f, 0.f, 0.f, 0.f, 0.f, 0.f, 0.f, 0.f};
  for (int b = 0; b < nb; ++b) {
#pragma unroll
    for (int t4 = 0; t4 < 16; t4 += 4) {
      int owner = gbase + (b << 2) + (t4 >> 2);        // lane owning slots r..r+3
      unsigned w0 = __shfl(u0, owner);
      unsigned w1 = __shfl(u1, owner);
      int s0 = w0 & 0xffff, s1 = w0 >> 16;
      int s2 = w1 & 0xffff, s3 = w1 >> 16;
      us8 v0 = *(const us8*)&h1n[(size_t)s0 * 128 + fl * 8];
      us8 v1 = *(const us8*)&h1n[(size_t)s1 * 128 + fl * 8];
      us8 v2 = *(const us8*)&h1n[(size_t)s2 * 128 + fl * 8];
      us8 v3 = *(const us8*)&h1n[(size_t)s3 * 128 + fl * 8];
#pragma unroll
      for (int j = 0; j < 8; ++j)
        acc[j] += (bf2f(v0[j]) + bf2f(v1[j])) + (bf2f(v2[j]) + bf2f(v3[j]));
    }
  }
  // epilogue: all 64 lanes active (4 nodes concurrently)
  float nd = norm_dst[node];
  float4 bb0 = *(const float4*)&b1[fl * 8];
  float4 bb1 = *(const float4*)&b1[fl * 8 + 4];
  float r[8];
  r[0] = fmaxf(acc[0] * nd + bb0.x, 0.f);
  r[1] = fmaxf(acc[1] * nd + bb0.y, 0.f);
  r[2] = fmaxf(acc[2] * nd + bb0.z, 0.f);
  r[3] = fmaxf(acc[3] * nd + bb0.w, 0.f);
  r[4] = fmaxf(acc[4] * nd + bb1.x, 0.f);
  r[5] = fmaxf(acc[5] * nd + bb1.y, 0.f);
  r[6] = fmaxf(acc[6] * nd + bb1.z, 0.f);
  r[7] = fmaxf(acc[7] * nd + bb1.w, 0.f);
  float4 pa = make_float4(0.f, 0.f, 0.f, 0.f);
  float4 pb = make_float4(0.f, 0.f, 0.f, 0.f);
#pragma unroll
  for (int jj = 0; jj < 8; ++jj) {
    float4 wa = *(const float4*)&W2[(fl * 8 + jj) * 8];
    float4 wb = *(const float4*)&W2[(fl * 8 + jj) * 8 + 4];
    pa.x += r[jj] * wa.x; pa.y += r[jj] * wa.y;
    pa.z += r[jj] * wa.z; pa.w += r[jj] * wa.w;
    pb.x += r[jj] * wb.x; pb.y += r[jj] * wb.y;
    pb.z += r[jj] * wb.z; pb.w += r[jj] * wb.w;
  }
  // group-local tree-reduce (d<16 stays inside the 16-lane group)
#pragma unroll
  for (int d = 8; d >= 1; d >>= 1) {
    pa.x += __shfl_down(pa.x, d); pa.y += __shfl_down(pa.y, d);
    pa.z += __shfl_down(pa.z, d); pa.w += __shfl_down(pa.w, d);
    pb.x += __shfl_down(pb.x, d); pb.y += __shfl_down(pb.y, d);
    pb.z += __shfl_down(pb.z, d); pb.w += __shfl_down(pb.w, d);
  }
  if (fl == 0) {
    float ns = norm_src[node];
    pa.x *= ns; pa.y *= ns; pa.z *= ns; pa.w *= ns;
    pb.x *= ns; pb.y *= ns; pb.z *= ns; pb.w *= ns;
    *(float4*)&h2n[(size_t)node * 8] = pa;
    *(float4*)&h2n[(size_t)node * 8 + 4] = pb;
  }
}

// ---------- layer-2 aggregation + mean-pool: sentinel-padded, 4 loads in flight ----------
__global__ __launch_bounds__(256) void k_agg2pool(const float* __restrict__ h2n,
                                                  const int* __restrict__ cnt,
                                                  const unsigned short* __restrict__ esrc16,
                                                  const float* __restrict__ norm_dst,
                                                  const float* __restrict__ b2,
                                                  const int* __restrict__ gids,
                                                  float* __restrict__ gsum, int N) {
  __shared__ float bins[16 * 8];
  __shared__ int sg0;
  int tid = threadIdx.x;
  if (tid < 128) bins[tid] = 0.f;
  int base = blockIdx.x * 32;
  if (tid == 0) sg0 = gids[min(base, N - 1)];
  __syncthreads();
  int node = base + (tid >> 3);
  int j = tid & 7;
  if (node < N) {
    int cp = (cnt[node] + 15) & ~15;
    int i0 = node * CAP;
    float acc = 0.f;
    for (int i = 0; i < cp; i += 4) {
      ushort4 ss = *(const ushort4*)&esrc16[i0 + i];   // group-uniform broadcast
      acc += (h2n[(size_t)ss.x * 8 + j] + h2n[(size_t)ss.y * 8 + j]) +
             (h2n[(size_t)ss.z * 8 + j] + h2n[(size_t)ss.w * 8 + j]);
    }
    float r = acc * norm_dst[node] + b2[j];
    int delta = gids[node] - sg0;
    if (delta < 16) atomicAdd(&bins[delta * 8 + j], r);
    else atomicAdd(&gsum[gids[node] * 8 + j], r);
  }
  __syncthreads();
  if (tid < 128) {
    float v = bins[tid];
    if (v != 0.f) atomicAdd(&gsum[(sg0 + (tid >> 3)) * 8 + (tid & 7)], v);
  }
}

// ---------- final ----------
__global__ void k_final(const float* __restrict__ gsum, const int* __restrict__ gids,
                        float* __restrict__ out, int NG, int N) {
  int i = blockIdx.x * 256 + threadIdx.x;
  if (i < NG * F2) {
    int g = i >> 3;
    int lo = 0, hi = N;
    while (lo < hi) { int m = (lo + hi) >> 1; if (gids[m] < g) lo = m + 1; else hi = m; }
    int lb = lo;
    lo = 0; hi = N;
    while (lo < hi) { int m = (lo + hi) >> 1; if (gids[m] <= g) lo = m + 1; else hi = m; }
    int cnt = lo - lb;
    out[i] = gsum[i] / fmaxf((float)cnt, 1.f);
  }
}

extern "C" void kernel_launch(void* const* d_in, const int* in_sizes, int n_in,
                              void* d_out, int out_size, void* d_ws, size_t ws_size,
                              hipStream_t stream) {
  const float* x  = (const float*)d_in[0];
  const float* W1 = (const float*)d_in[1];
  const float* b1 = (const float*)d_in[2];
  const float* W2 = (const float*)d_in[3];
  const float* b2 = (const float*)d_in[4];
  const int* src  = (const int*)d_in[5];
  const int* dst  = (const int*)d_in[6];
  const int* gids = (const int*)d_in[7];
  int N = in_sizes[0] / F1;
  int E = in_sizes[5];
  int NG = out_size / F2;
  float* out = (float*)d_out;

  int Epad = (E + 2047) & ~2047;            // multiple of 256*8
  int NR  = (N + RH - 1) / RH;              // node ranges
  int NCH = (Epad + ECH - 1) / ECH;         // edge chunks

  char* p = (char*)d_ws;
  auto alloc = [&](size_t bytes) -> void* {
    void* r = (void*)p;
    p += (bytes + 255) & ~(size_t)255;
    return r;
  };
  float* gsum    = (float*)alloc((size_t)NG * F2 * 4);
  unsigned short* src16 = (unsigned short*)alloc((size_t)Epad * 2);
  unsigned short* dst16 = (unsigned short*)alloc((size_t)Epad * 2);
  int* cnt       = (int*)alloc((size_t)N * 4);
  float* norm_src = (float*)alloc((size_t)N * 4);
  float* norm_dst = (float*)alloc((size_t)N * 4);
  unsigned short* esrc16 = (unsigned short*)alloc((size_t)N * CAP * 2);
  unsigned short* h1n = (unsigned short*)alloc((size_t)(N + 1) * F1 * 2);  // +1 sentinel row
  float* h2n     = (float*)alloc((size_t)(N + 1) * F2 * 4);                // +1 sentinel row
  int* partialA  = (int*)alloc((size_t)NCH * N * 4);
  int* partialB  = (int*)alloc((size_t)NCH * N * 4);
  int* starts    = (int*)alloc((size_t)NCH * N * 4);
  (void)ws_size; (void)n_in;

  k_hist<<<dim3(NR, NCH), 256, 0, stream>>>(src, dst, src16, dst16,
                                            partialA, partialB, Epad, E, N);
  k_starts<<<(N + 255) / 256, 256, 0, stream>>>(partialA, partialB, starts, cnt,
                                                norm_src, norm_dst, esrc16, h1n, h2n,
                                                gsum, N, NCH, NG * F2);
  k_scatter<<<dim3(NR, NCH), 256, 0, stream>>>(src16, dst16, starts, esrc16, Epad, N);
  k_gemm1<<<(N + 127) / 128, 256, 0, stream>>>(x, W1, norm_src, h1n, N);
  k_agg1f<<<(N + 15) / 16, 256, 0, stream>>>(h1n, cnt, esrc16, norm_dst, norm_src, b1, W2, h2n, N);
  k_agg2pool<<<((N * 8 + 255) / 256), 256, 0, stream>>>(h2n, cnt, esrc16, norm_dst, b2, gids, gsum, N);
  k_final<<<(NG * F2 + 255) / 256, 256, 0, stream>>>(gsum, gids, out, NG, N);
}